// Round 6
// baseline (21914.655 us; speedup 1.0000x reference)
//
#include <hip/hip_runtime.h>
#include <hip/hip_bf16.h>

#define B_ 128
#define T_ 2048
#define D_ 128
#define H_ 512
#define L_ 10

typedef __attribute__((ext_vector_type(8))) short short8;
typedef __attribute__((ext_vector_type(4))) float f32x4;

__device__ __forceinline__ unsigned short f2bf(float f) {
    union { float f; unsigned u; } v; v.f = f;
    unsigned r = v.u + 0x7fffu + ((v.u >> 16) & 1u);
    return (unsigned short)(r >> 16);
}
__device__ __forceinline__ float fast_sig(float x) {
    return 1.f / (1.f + __expf(-x));
}
__device__ __forceinline__ float fast_tanh(float x) {
    return 1.f - 2.f / (__expf(2.f * x) + 1.f);
}
#define MFMA(a, b, c) __builtin_amdgcn_mfma_f32_16x16x32_bf16(a, b, c, 0, 0, 0)

// Persistent LSTM. Grid = 64 WGs x 512 thr = 8 groups x (8 WGs x 8 waves).
// Wave pair per hu-tile: tile = wave>>1 (4 tiles/WG), kh = wave&1 splits
// K=640 into kk 0..9 (kh=0) and kk 10..19 (kh=1, includes the x part).
// Weights: 4 gates x 10 kk = 160 VGPRs/lane (HALF of R3..R5's 320 --
// R3/R4/R5 failed bit-identically under 3 different exchange layouts;
// prime suspect is the register-extreme config, this round halves it).
// kh=1 passes its partial sums via LDS (1 barrier/step); cell stays
// in-register in kh=0 with all 4 gates. h exchange: natural [2][128][512]
// bf16 layout, relaxed agent u32 atomics (R2-validated widths).
__global__ __launch_bounds__(512, 1) void lstm_kernel(
    const float* __restrict__ x, const float* __restrict__ W_ih,
    const float* __restrict__ W_hh, const float* __restrict__ bias,
    unsigned int* h_nat,          // [2][128][512] bf16 as u32[2][32768]
    unsigned int* flags,          // [8][32] u32 (padded)
    float* __restrict__ hfin)     // [128][512] fp32
{
    const int g    = blockIdx.x & 7;
    const int sb   = blockIdx.x >> 3;     // 0..7
    const int w    = threadIdx.x >> 6;    // 0..7
    const int tile = w >> 1;              // 0..3
    const int kh   = w & 1;               // k-half
    const int ws   = sb * 4 + tile;       // hu-tile 0..31
    const int lane = threadIdx.x & 63;
    const int n    = lane & 15;           // batch col / A-row m
    const int quad = lane >> 4;
    const int bb   = g * 16 + n;

    // partial-sum exchange: [tile][lane][16 used, stride 20 floats for banks]
    __shared__ float part[4][64][20];     // 20480 B

    // ---- one-time: weight A-fragments, 4 gates x 10 kk = 160 VGPRs ----
    // A[m=lane&15][k=quad*8+j]; row r = gate*512 + ws*16 + m; K=[h(512)|x(128)]
    short8 wf[4][10];
    #pragma unroll
    for (int q = 0; q < 4; ++q) {
        const int r = q * 512 + ws * 16 + n;
        #pragma unroll
        for (int j = 0; j < 10; ++j) {
            const int k0 = (kh * 10 + j) * 32 + quad * 8;
            short8 v;
            #pragma unroll
            for (int e = 0; e < 8; ++e) {
                const int k = k0 + e;
                const float f = (k < 512) ? W_hh[(size_t)r * 512 + k]
                                          : W_ih[(size_t)r * 128 + (k - 512)];
                v[e] = (short)f2bf(f);
            }
            wf[q][j] = v;
        }
    }

    float bs[4][4];
    #pragma unroll
    for (int q = 0; q < 4; ++q)
        #pragma unroll
        for (int rr = 0; rr < 4; ++rr)
            bs[q][rr] = bias[q * 512 + ws * 16 + quad * 4 + rr];

    float c_val[4] = {0.f, 0.f, 0.f, 0.f};   // used by kh=0 only

    unsigned int* myflag = flags + g * 32 + ws;
    const unsigned int* pollflag = flags + g * 32 + (lane & 31);

    for (int t = 0; t < T_; ++t) {
        // ---- kh=1: x fragments (global kk 16..19) before poll ----
        short8 xb[4];
        if (kh) {
            #pragma unroll
            for (int kx = 0; kx < 4; ++kx) {
                const float* xp = x + ((size_t)bb * T_ + t) * D_ + kx * 32 + quad * 8;
                union { float4 f4; float f[4]; } a, b2;
                a.f4  = *(const float4*)xp;
                b2.f4 = *(const float4*)(xp + 4);
                short8 v;
                #pragma unroll
                for (int j = 0; j < 4; ++j) v[j] = (short)f2bf(a.f[j]);
                #pragma unroll
                for (int j = 0; j < 4; ++j) v[4 + j] = (short)f2bf(b2.f[j]);
                xb[kx] = v;
            }
        }

        // ---- poll the 32 per-tile flags ----
        if (t > 0) {
            unsigned int v;
            do {
                v = __hip_atomic_load(pollflag, __ATOMIC_RELAXED,
                                      __HIP_MEMORY_SCOPE_AGENT);
            } while (__any((int)(v < (unsigned int)t)));
        }
        __asm__ __volatile__("" ::: "memory");

        const unsigned int* src = h_nat + (size_t)(t & 1) * 32768;
        union HB { unsigned int u[4]; short8 v; };

        f32x4 a0 = {0,0,0,0}, a1 = {0,0,0,0}, a2 = {0,0,0,0}, a3 = {0,0,0,0};
        if (kh == 0) {
            HB hb[10];
            #pragma unroll
            for (int j = 0; j < 10; ++j) {
                const unsigned int* p = src + (size_t)bb * 256 + j * 16 + quad * 4;
                #pragma unroll
                for (int e = 0; e < 4; ++e)
                    hb[j].u[e] = __hip_atomic_load(p + e, __ATOMIC_RELAXED,
                                                   __HIP_MEMORY_SCOPE_AGENT);
            }
            #pragma unroll
            for (int j = 0; j < 10; ++j) {
                const short8 b = hb[j].v;
                a0 = MFMA(wf[0][j], b, a0);
                a1 = MFMA(wf[1][j], b, a1);
                a2 = MFMA(wf[2][j], b, a2);
                a3 = MFMA(wf[3][j], b, a3);
            }
        } else {
            HB hb[6];
            #pragma unroll
            for (int j = 0; j < 6; ++j) {
                const unsigned int* p = src + (size_t)bb * 256 + (10 + j) * 16 + quad * 4;
                #pragma unroll
                for (int e = 0; e < 4; ++e)
                    hb[j].u[e] = __hip_atomic_load(p + e, __ATOMIC_RELAXED,
                                                   __HIP_MEMORY_SCOPE_AGENT);
            }
            #pragma unroll
            for (int j = 0; j < 6; ++j) {
                const short8 b = hb[j].v;
                a0 = MFMA(wf[0][j], b, a0);
                a1 = MFMA(wf[1][j], b, a1);
                a2 = MFMA(wf[2][j], b, a2);
                a3 = MFMA(wf[3][j], b, a3);
            }
            #pragma unroll
            for (int kx = 0; kx < 4; ++kx) {
                const short8 b = xb[kx];
                a0 = MFMA(wf[0][6 + kx], b, a0);
                a1 = MFMA(wf[1][6 + kx], b, a1);
                a2 = MFMA(wf[2][6 + kx], b, a2);
                a3 = MFMA(wf[3][6 + kx], b, a3);
            }
            // publish partials for the cell wave (same lane = same (hu,batch))
            *(f32x4*)&part[tile][lane][0]  = a0;
            *(f32x4*)&part[tile][lane][4]  = a1;
            *(f32x4*)&part[tile][lane][8]  = a2;
            *(f32x4*)&part[tile][lane][12] = a3;
        }

        __syncthreads();

        if (kh == 0) {
            const f32x4 p0 = *(const f32x4*)&part[tile][lane][0];
            const f32x4 p1 = *(const f32x4*)&part[tile][lane][4];
            const f32x4 p2 = *(const f32x4*)&part[tile][lane][8];
            const f32x4 p3 = *(const f32x4*)&part[tile][lane][12];
            float hh[4];
            #pragma unroll
            for (int rr = 0; rr < 4; ++rr) {
                const float gi = a0[rr] + p0[rr] + bs[0][rr];
                const float gf = a1[rr] + p1[rr] + bs[1][rr];
                const float gg = a2[rr] + p2[rr] + bs[2][rr];
                const float go = a3[rr] + p3[rr] + bs[3][rr];
                c_val[rr] = fast_sig(gf) * c_val[rr] + fast_sig(gi) * fast_tanh(gg);
                hh[rr] = fast_sig(go) * fast_tanh(c_val[rr]);
            }
            // h_{t+1}: hu = ws*16 + quad*4 + rr of row bb -> two adjacent u32
            const unsigned int lo = (unsigned int)f2bf(hh[0]) |
                                    ((unsigned int)f2bf(hh[1]) << 16);
            const unsigned int hi = (unsigned int)f2bf(hh[2]) |
                                    ((unsigned int)f2bf(hh[3]) << 16);
            unsigned int* dst = h_nat + (size_t)((t + 1) & 1) * 32768
                              + (size_t)bb * 256 + ws * 8 + quad * 2;
            __hip_atomic_store(dst,     lo, __ATOMIC_RELAXED, __HIP_MEMORY_SCOPE_AGENT);
            __hip_atomic_store(dst + 1, hi, __ATOMIC_RELAXED, __HIP_MEMORY_SCOPE_AGENT);
            if (t == T_ - 1) {
                #pragma unroll
                for (int rr = 0; rr < 4; ++rr)
                    hfin[(size_t)bb * 512 + ws * 16 + quad * 4 + rr] = hh[rr];
            }
        }

        __asm__ __volatile__("s_waitcnt vmcnt(0)" ::: "memory");  // drain h stores
        if (kh == 0 && lane == 0)
            __hip_atomic_store(myflag, (unsigned int)(t + 1), __ATOMIC_RELAXED,
                               __HIP_MEMORY_SCOPE_AGENT);
    }
}

// Head: logits = h_final @ W_out^T, softmax. One wave per batch row.
__global__ void head_kernel(const float* __restrict__ hfin,
                            const float* __restrict__ W_out,
                            float* __restrict__ out)
{
    const int bidx = blockIdx.x;
    const int l    = threadIdx.x;      // 0..63
    float hv[8];
    #pragma unroll
    for (int j = 0; j < 8; ++j) hv[j] = hfin[bidx * 512 + j * 64 + l];
    __shared__ float logits[L_];
    for (int o = 0; o < L_; ++o) {
        float p = 0.f;
        #pragma unroll
        for (int j = 0; j < 8; ++j) p += hv[j] * W_out[o * 512 + j * 64 + l];
        #pragma unroll
        for (int off = 32; off; off >>= 1) p += __shfl_down(p, off, 64);
        if (l == 0) logits[o] = p;
    }
    __syncthreads();
    if (l == 0) {
        float mx = logits[0];
        for (int o = 1; o < L_; ++o) mx = fmaxf(mx, logits[o]);
        float e[L_], sum = 0.f;
        for (int o = 0; o < L_; ++o) { e[o] = __expf(logits[o] - mx); sum += e[o]; }
        const float inv = 1.f / sum;
        for (int o = 0; o < L_; ++o) out[bidx * L_ + o] = e[o] * inv;
    }
}

extern "C" void kernel_launch(void* const* d_in, const int* in_sizes, int n_in,
                              void* d_out, int out_size, void* d_ws, size_t ws_size,
                              hipStream_t stream) {
    const float* x     = (const float*)d_in[0];
    const float* W_ih  = (const float*)d_in[1];
    const float* W_hh  = (const float*)d_in[2];
    const float* bias  = (const float*)d_in[3];
    const float* W_out = (const float*)d_in[4];
    float* out = (float*)d_out;

    // ws: h_nat [2][128][512] bf16 (262144 B) | flags [8][32] u32 (pad 4096)
    //   | hfin [128][512] f32 (262144 B)
    char* ws = (char*)d_ws;
    unsigned int* h_nat = (unsigned int*)ws;
    unsigned int* flags = (unsigned int*)(ws + 262144);
    float*        hfin  = (float*)(ws + 262144 + 4096);

    hipMemsetAsync(ws, 0, 262144 + 4096, stream);  // zero h0 + flags

    void* args[] = { (void*)&x, (void*)&W_ih, (void*)&W_hh, (void*)&bias,
                     (void*)&h_nat, (void*)&flags, (void*)&hfin };
    hipLaunchCooperativeKernel((void*)lstm_kernel, dim3(64), dim3(512),
                               args, 0, stream);
    head_kernel<<<dim3(B_), dim3(64), 0, stream>>>(hfin, W_out, out);
}

// Round 7
// 8737.099 us; speedup vs baseline: 2.5082x; 2.5082x over previous
//
#include <hip/hip_runtime.h>
#include <hip/hip_bf16.h>

#define B_ 128
#define T_ 2048
#define D_ 128
#define H_ 512
#define L_ 10

typedef __attribute__((ext_vector_type(8))) short short8;
typedef __attribute__((ext_vector_type(4))) float f32x4;

__device__ __forceinline__ unsigned short f2bf(float f) {
    union { float f; unsigned u; } v; v.f = f;
    unsigned r = v.u + 0x7fffu + ((v.u >> 16) & 1u);
    return (unsigned short)(r >> 16);
}
__device__ __forceinline__ float fast_sig(float x) {
    return 1.f / (1.f + __expf(-x));
}
__device__ __forceinline__ float fast_tanh(float x) {
    return 1.f - 2.f / (__expf(2.f * x) + 1.f);
}
#define MFMA(a, b, c) __builtin_amdgcn_mfma_f32_16x16x32_bf16(a, b, c, 0, 0, 0)

// Persistent LSTM. Grid = 256 WGs x 256 thr = 8 groups x 32 tiles x 4 waves.
// WG = one hu-tile (16 hu x 4 gates x 16 batches); its 4 waves split K=640
// into 5 kk each (w*5+j). Weights: 4 gates x 5 kk x 4 VGPR = 80 VGPRs/lane
// (R6's 160 spilled at VGPR_Count=128 -> 10.5us/step scratch reloads; this
// halves demand and pins the cap via __launch_bounds__(256,2) = 256 regs).
// Waves 1..3 pass partials through LDS ([64][20] stride: 0 conflicts in R6);
// wave 0 reduces + in-register cell + publishes h. h exchange: natural
// [2][128][512] bf16 layout, relaxed agent u32 atomics (R2/R6-validated).
// Race-freedom of part[] reuse: waves 1..3 re-write only after their poll
// sees own-tile flag >= t+1, which wave 0 sets after reading the partials.
__global__ __launch_bounds__(256, 2) void lstm_kernel(
    const float* __restrict__ x, const float* __restrict__ W_ih,
    const float* __restrict__ W_hh, const float* __restrict__ bias,
    unsigned int* h_nat,          // [2][128][512] bf16 as u32[2][32768]
    unsigned int* flags,          // [8][32] u32 (padded)
    float* __restrict__ hfin)     // [128][512] fp32
{
    const int g    = blockIdx.x & 7;
    const int ws   = blockIdx.x >> 3;     // hu-tile 0..31
    const int w    = threadIdx.x >> 6;    // k-quarter 0..3
    const int lane = threadIdx.x & 63;
    const int n    = lane & 15;           // batch col / A-row m
    const int quad = lane >> 4;
    const int bb   = g * 16 + n;

    __shared__ float part[3][64][20];     // 15360 B, stride-20 (conflict-free)

    // ---- one-time: weight A-fragments, 4 gates x 5 kk = 80 VGPRs ----
    // A[m=lane&15][k=quad*8+j]; row r = gate*512 + ws*16 + m; K=[h(512)|x(128)]
    short8 wf[4][5];
    #pragma unroll
    for (int q = 0; q < 4; ++q) {
        const int r = q * 512 + ws * 16 + n;
        #pragma unroll
        for (int j = 0; j < 5; ++j) {
            const int k0 = (w * 5 + j) * 32 + quad * 8;
            short8 v;
            #pragma unroll
            for (int e = 0; e < 8; ++e) {
                const int k = k0 + e;
                const float f = (k < 512) ? W_hh[(size_t)r * 512 + k]
                                          : W_ih[(size_t)r * 128 + (k - 512)];
                v[e] = (short)f2bf(f);
            }
            wf[q][j] = v;
        }
    }

    float bs[4][4];
    #pragma unroll
    for (int q = 0; q < 4; ++q)
        #pragma unroll
        for (int rr = 0; rr < 4; ++rr)
            bs[q][rr] = bias[q * 512 + ws * 16 + quad * 4 + rr];

    float c_val[4] = {0.f, 0.f, 0.f, 0.f};   // live in wave 0 only

    unsigned int* myflag = flags + g * 32 + ws;
    const unsigned int* pollflag = flags + g * 32 + (lane & 31);

    for (int t = 0; t < T_; ++t) {
        // ---- wave 3: x fragments (kk 16..19 = its j 1..4), before poll ----
        short8 xb[4];
        if (w == 3) {
            #pragma unroll
            for (int kx = 0; kx < 4; ++kx) {
                const float* xp = x + ((size_t)bb * T_ + t) * D_ + kx * 32 + quad * 8;
                union { float4 f4; float f[4]; } a, b2;
                a.f4  = *(const float4*)xp;
                b2.f4 = *(const float4*)(xp + 4);
                short8 v;
                #pragma unroll
                for (int j = 0; j < 4; ++j) v[j] = (short)f2bf(a.f[j]);
                #pragma unroll
                for (int j = 0; j < 4; ++j) v[4 + j] = (short)f2bf(b2.f[j]);
                xb[kx] = v;
            }
        }

        // ---- poll the group's 32 per-tile flags (coalesced, all waves) ----
        if (t > 0) {
            unsigned int v;
            do {
                v = __hip_atomic_load(pollflag, __ATOMIC_RELAXED,
                                      __HIP_MEMORY_SCOPE_AGENT);
            } while (__any((int)(v < (unsigned int)t)));
        }
        __asm__ __volatile__("" ::: "memory");

        const unsigned int* src = h_nat + (size_t)(t & 1) * 32768;
        union HB { unsigned int u[4]; short8 v; };

        f32x4 a0 = {0,0,0,0}, a1 = {0,0,0,0}, a2 = {0,0,0,0}, a3 = {0,0,0,0};
        if (w < 3) {
            HB hb[5];
            #pragma unroll
            for (int j = 0; j < 5; ++j) {
                const unsigned int* p = src + (size_t)bb * 256 + (w * 5 + j) * 16 + quad * 4;
                #pragma unroll
                for (int e = 0; e < 4; ++e)
                    hb[j].u[e] = __hip_atomic_load(p + e, __ATOMIC_RELAXED,
                                                   __HIP_MEMORY_SCOPE_AGENT);
            }
            #pragma unroll
            for (int j = 0; j < 5; ++j) {
                const short8 b = hb[j].v;
                a0 = MFMA(wf[0][j], b, a0);
                a1 = MFMA(wf[1][j], b, a1);
                a2 = MFMA(wf[2][j], b, a2);
                a3 = MFMA(wf[3][j], b, a3);
            }
        } else {
            HB hb0;   // kk 15 (last h fragment)
            const unsigned int* p = src + (size_t)bb * 256 + 15 * 16 + quad * 4;
            #pragma unroll
            for (int e = 0; e < 4; ++e)
                hb0.u[e] = __hip_atomic_load(p + e, __ATOMIC_RELAXED,
                                             __HIP_MEMORY_SCOPE_AGENT);
            {
                const short8 b = hb0.v;
                a0 = MFMA(wf[0][0], b, a0);
                a1 = MFMA(wf[1][0], b, a1);
                a2 = MFMA(wf[2][0], b, a2);
                a3 = MFMA(wf[3][0], b, a3);
            }
            #pragma unroll
            for (int kx = 0; kx < 4; ++kx) {
                const short8 b = xb[kx];
                a0 = MFMA(wf[0][1 + kx], b, a0);
                a1 = MFMA(wf[1][1 + kx], b, a1);
                a2 = MFMA(wf[2][1 + kx], b, a2);
                a3 = MFMA(wf[3][1 + kx], b, a3);
            }
        }

        if (w > 0) {
            *(f32x4*)&part[w - 1][lane][0]  = a0;
            *(f32x4*)&part[w - 1][lane][4]  = a1;
            *(f32x4*)&part[w - 1][lane][8]  = a2;
            *(f32x4*)&part[w - 1][lane][12] = a3;
        }
        __syncthreads();

        if (w == 0) {
            #pragma unroll
            for (int j = 0; j < 3; ++j) {
                a0 += *(const f32x4*)&part[j][lane][0];
                a1 += *(const f32x4*)&part[j][lane][4];
                a2 += *(const f32x4*)&part[j][lane][8];
                a3 += *(const f32x4*)&part[j][lane][12];
            }
            float hh[4];
            #pragma unroll
            for (int rr = 0; rr < 4; ++rr) {
                const float gi = a0[rr] + bs[0][rr];
                const float gf = a1[rr] + bs[1][rr];
                const float gg = a2[rr] + bs[2][rr];
                const float go = a3[rr] + bs[3][rr];
                c_val[rr] = fast_sig(gf) * c_val[rr] + fast_sig(gi) * fast_tanh(gg);
                hh[rr] = fast_sig(go) * fast_tanh(c_val[rr]);
            }
            // h_{t+1}: hu = ws*16 + quad*4 + rr of row bb -> two adjacent u32
            const unsigned int lo = (unsigned int)f2bf(hh[0]) |
                                    ((unsigned int)f2bf(hh[1]) << 16);
            const unsigned int hi = (unsigned int)f2bf(hh[2]) |
                                    ((unsigned int)f2bf(hh[3]) << 16);
            unsigned int* dst = h_nat + (size_t)((t + 1) & 1) * 32768
                              + (size_t)bb * 256 + ws * 8 + quad * 2;
            __hip_atomic_store(dst,     lo, __ATOMIC_RELAXED, __HIP_MEMORY_SCOPE_AGENT);
            __hip_atomic_store(dst + 1, hi, __ATOMIC_RELAXED, __HIP_MEMORY_SCOPE_AGENT);
            if (t == T_ - 1) {
                #pragma unroll
                for (int rr = 0; rr < 4; ++rr)
                    hfin[(size_t)bb * 512 + ws * 16 + quad * 4 + rr] = hh[rr];
            }
            __asm__ __volatile__("s_waitcnt vmcnt(0)" ::: "memory");  // drain h
            if (lane == 0)
                __hip_atomic_store(myflag, (unsigned int)(t + 1), __ATOMIC_RELAXED,
                                   __HIP_MEMORY_SCOPE_AGENT);
        }
    }
}

// Head: logits = h_final @ W_out^T, softmax. One wave per batch row.
__global__ void head_kernel(const float* __restrict__ hfin,
                            const float* __restrict__ W_out,
                            float* __restrict__ out)
{
    const int bidx = blockIdx.x;
    const int l    = threadIdx.x;      // 0..63
    float hv[8];
    #pragma unroll
    for (int j = 0; j < 8; ++j) hv[j] = hfin[bidx * 512 + j * 64 + l];
    __shared__ float logits[L_];
    for (int o = 0; o < L_; ++o) {
        float p = 0.f;
        #pragma unroll
        for (int j = 0; j < 8; ++j) p += hv[j] * W_out[o * 512 + j * 64 + l];
        #pragma unroll
        for (int off = 32; off; off >>= 1) p += __shfl_down(p, off, 64);
        if (l == 0) logits[o] = p;
    }
    __syncthreads();
    if (l == 0) {
        float mx = logits[0];
        for (int o = 1; o < L_; ++o) mx = fmaxf(mx, logits[o]);
        float e[L_], sum = 0.f;
        for (int o = 0; o < L_; ++o) { e[o] = __expf(logits[o] - mx); sum += e[o]; }
        const float inv = 1.f / sum;
        for (int o = 0; o < L_; ++o) out[bidx * L_ + o] = e[o] * inv;
    }
}

extern "C" void kernel_launch(void* const* d_in, const int* in_sizes, int n_in,
                              void* d_out, int out_size, void* d_ws, size_t ws_size,
                              hipStream_t stream) {
    const float* x     = (const float*)d_in[0];
    const float* W_ih  = (const float*)d_in[1];
    const float* W_hh  = (const float*)d_in[2];
    const float* bias  = (const float*)d_in[3];
    const float* W_out = (const float*)d_in[4];
    float* out = (float*)d_out;

    // ws: h_nat [2][128][512] bf16 (262144 B) | flags [8][32] u32 (pad 4096)
    //   | hfin [128][512] f32 (262144 B)
    char* ws = (char*)d_ws;
    unsigned int* h_nat = (unsigned int*)ws;
    unsigned int* flags = (unsigned int*)(ws + 262144);
    float*        hfin  = (float*)(ws + 262144 + 4096);

    hipMemsetAsync(ws, 0, 262144 + 4096, stream);  // zero h0 + flags

    void* args[] = { (void*)&x, (void*)&W_ih, (void*)&W_hh, (void*)&bias,
                     (void*)&h_nat, (void*)&flags, (void*)&hfin };
    hipLaunchCooperativeKernel((void*)lstm_kernel, dim3(256), dim3(256),
                               args, 0, stream);
    head_kernel<<<dim3(B_), dim3(64), 0, stream>>>(hfin, W_out, out);
}